// Round 2
// baseline (99.408 us; speedup 1.0000x reference)
//
#include <hip/hip_runtime.h>

// Chamfer loss: B=8, P=32, N=M=1024, fp32 in, scalar fp32 out.
// Reference quirk: x[bp,m,c] = rp[bp, (3m+c)%M, (3m+c)>>10]  (torch permute+reshape).
//
// R6: R5's bit-exact MFMA formulation (3-way bf16 split, 30 K-slots, 2x
// mfma_f32_32x32x16_bf16 per 32x32 tile), restructured for occupancy and
// register residency:
//  - 1024 threads / 16 waves, wave owns 64 rows = 2 stripes (was 512/8/4).
//    Persistent state: rmin[2][16]=32 + af[2][2]=16 + acc 16 + temps ~= 100
//    regs -> fits __launch_bounds__(1024,4)'s 128-VGPR budget => no AGPR
//    round-trips (R5: VGPR_Count=96 + accvgpr copies tripled VALU instrs).
//  - 4 waves/SIMD (was 2) hides MFMA->fmin, LDS and bpermute latency.
//  - colW overlay becomes 16x1024 f32 = exactly the dead 64KB A panel.

#define MM 1024
#define NN 1024
#define THREADS 1024
#define NWAVES 16
#define FINF 3.4e38f

typedef float f32x16 __attribute__((ext_vector_type(16)));
typedef __bf16 bf16x8 __attribute__((ext_vector_type(8)));

#define B_STRIDE 80                       // bytes per y-column (40 ushort slots)
#define A_STRIDE 64                       // bytes per x-row (32 ushort slots)
#define B_OFF 0
#define A_OFF (NN * B_STRIDE)             // 81920
#define CW_OFF A_OFF                      // overlay: colW[16][1024] f32 = 64KB
#define RS_OFF (A_OFF + MM * A_STRIDE)    // 147456
#define RED_OFF (RS_OFF + 128)            // 32 rowsum slots
#define LDS_BYTES (RED_OFF + 64)          // 147648

__device__ __forceinline__ unsigned short bf16_rne(float v) {
    unsigned u = __float_as_uint(v);
    u = u + 0x7FFFu + ((u >> 16) & 1u);
    return (unsigned short)(u >> 16);
}
__device__ __forceinline__ float bf16f(unsigned short h) {
    return __uint_as_float(((unsigned)h) << 16);
}
struct S3 { unsigned short h0, h1, h2; };
__device__ __forceinline__ S3 split3(float v) {
    S3 o;
    o.h0 = bf16_rne(v);
    float r = v - bf16f(o.h0);
    o.h1 = bf16_rne(r);
    float r2 = r - bf16f(o.h1);
    o.h2 = bf16_rne(r2);
    return o;
}
__device__ __forceinline__ unsigned pk(unsigned short a, unsigned short b) {
    return (unsigned)a | ((unsigned)b << 16);
}
__device__ __forceinline__ float min3f(float a, float b, float c) {
    return fminf(fminf(a, b), c);   // folds to v_min3_f32
}
template <int CTRL>
__device__ __forceinline__ float dpp_ror_min(float v) {
    int vi = __float_as_int(v);
    int t  = __builtin_amdgcn_update_dpp(vi, vi, CTRL, 0xf, 0xf, true);
    return fminf(v, __int_as_float(t));
}

__global__ __launch_bounds__(THREADS, 4)
void chamfer_kernel(const float* __restrict__ nrf,   // (BP, N, 3) -> y
                    const float* __restrict__ rp,    // (BP, M, 3) -> x (scrambled)
                    float* __restrict__ out,
                    float inv_bpm, float inv_bpn) {
    __shared__ __align__(16) unsigned char smem[LDS_BYTES];
    unsigned char* Bb = smem + B_OFF;
    unsigned short* As = (unsigned short*)(smem + A_OFF);
    float* colW = (float*)(smem + CW_OFF);
    float* rowsumS = (float*)(smem + RS_OFF);
    float* redS = (float*)(smem + RED_OFF);

    const int bp = blockIdx.x;
    const int tid = threadIdx.x;
    const int lane = tid & 63;
    const int wave = tid >> 6;
    const int l31 = lane & 31;
    const int lh = lane >> 5;
    const unsigned short ONE = 0x3F80;

    const float* yB = nrf + (size_t)bp * NN * 3;
    const float* xB = rp + (size_t)bp * MM * 3;

    // ---- B panel: per col slots (b = y split, q = yy split)
    {
        const int c = tid;
        float y0 = yB[c * 3 + 0], y1 = yB[c * 3 + 1], y2 = yB[c * 3 + 2];
        float yy = __builtin_fmaf(y0, y0, __builtin_fmaf(y1, y1, y2 * y2));
        S3 b0 = split3(y0), b1 = split3(y1), b2 = split3(y2), q = split3(yy);
        uint4* dst = (uint4*)(Bb + c * B_STRIDE);
        dst[0] = make_uint4(pk(b0.h0, b0.h1), pk(b0.h0, b0.h1), pk(b0.h2, b0.h0), pk(b1.h0, b1.h1));
        dst[1] = make_uint4(pk(b1.h0, b1.h1), pk(b1.h2, b1.h0), pk(b2.h0, b2.h1), pk(b2.h0, b2.h1));
        dst[2] = make_uint4(pk(b2.h2, b2.h0), pk(ONE, ONE), pk(ONE, q.h0), pk(q.h1, q.h2));
        dst[3] = make_uint4(pk(b0.h2, b0.h1), pk(b1.h2, b1.h1), pk(b2.h2, b2.h1), 0u);
        dst[4] = make_uint4(0u, 0u, 0u, 0u);
    }
    // ---- A panel: per row slots (a = -2x split, p = xx split)
    {
        const int m = tid;
        int k = 3 * m;
        float x0 = xB[((k    ) & (MM - 1)) * 3 + ((k    ) >> 10)];
        float x1 = xB[((k + 1) & (MM - 1)) * 3 + ((k + 1) >> 10)];
        float x2 = xB[((k + 2) & (MM - 1)) * 3 + ((k + 2) >> 10)];
        float xx = __builtin_fmaf(x0, x0, __builtin_fmaf(x1, x1, x2 * x2));
        S3 a0 = split3(-2.0f * x0), a1 = split3(-2.0f * x1), a2 = split3(-2.0f * x2);
        S3 p = split3(xx);
        uint4* dst = (uint4*)((unsigned char*)As + m * A_STRIDE);
        dst[0] = make_uint4(pk(a0.h0, a0.h0), pk(a0.h1, a0.h1), pk(a0.h0, a0.h2), pk(a1.h0, a1.h0));
        dst[1] = make_uint4(pk(a1.h1, a1.h1), pk(a1.h0, a1.h2), pk(a2.h0, a2.h0), pk(a2.h1, a2.h1));
        dst[2] = make_uint4(pk(a2.h0, a2.h2), pk(p.h0, p.h1), pk(p.h2, ONE), pk(ONE, ONE));
        dst[3] = make_uint4(pk(a0.h1, a0.h2), pk(a1.h1, a1.h2), pk(a2.h1, a2.h2), 0u);
    }
    __syncthreads();

    // ---- A-fragment loads (once; rows fixed per wave): 2 stripes x 2 K-halves
    const int m0 = wave * 64;
    bf16x8 af[2][2];
    #pragma unroll
    for (int s = 0; s < 2; ++s) {
        #pragma unroll
        for (int h = 0; h < 2; ++h)
            af[s][h] = *(const bf16x8*)(As + (m0 + s * 32 + l31) * 32 + h * 16 + lh * 8);
    }
    __syncthreads();   // after this, A panel is colW

    float rmin[2][16];
    #pragma unroll
    for (int s = 0; s < 2; ++s)
        #pragma unroll
        for (int j = 0; j < 16; ++j) rmin[s][j] = FINF;

    f32x16 Z = {};
    const unsigned char* bptr = Bb + l31 * B_STRIDE + lh * 16;
    const int xaddr32 = (lane ^ 32) << 2;
    float* colWrow = colW + wave * 1024;

    bf16x8 bf0 = *(const bf16x8*)(bptr);
    bf16x8 bf1 = *(const bf16x8*)(bptr + 32);
    for (int t = 0; t < 32; ++t) {
        // prefetch next tile's B-frags (last iter reads dead LDS, values unused)
        const unsigned char* np = bptr + 32 * B_STRIDE;
        bf16x8 nb0 = *(const bf16x8*)(np);
        bf16x8 nb1 = *(const bf16x8*)(np + 32);

        float cm = FINF;
        #pragma unroll
        for (int s = 0; s < 2; ++s) {
            f32x16 acc = __builtin_amdgcn_mfma_f32_32x32x16_bf16(af[s][0], bf0, Z, 0, 0, 0);
            acc = __builtin_amdgcn_mfma_f32_32x32x16_bf16(af[s][1], bf1, acc, 0, 0, 0);
            #pragma unroll
            for (int j = 0; j < 16; ++j) rmin[s][j] = fminf(rmin[s][j], acc[j]);
            float u0 = min3f(acc[0], acc[1], acc[2]);
            float u1 = min3f(acc[3], acc[4], acc[5]);
            float u2 = min3f(acc[6], acc[7], acc[8]);
            float u3 = min3f(acc[9], acc[10], acc[11]);
            float u4 = min3f(acc[12], acc[13], acc[14]);
            cm = fminf(cm, fminf(min3f(u0, u1, u2), min3f(u3, u4, acc[15])));
        }
        // merge the two lane-halves -> full 64-row col-min for this wave
        int pz = __builtin_amdgcn_ds_bpermute(xaddr32, __float_as_int(cm));
        cm = fminf(cm, __int_as_float(pz));
        if (lh == 0) colWrow[t * 32 + l31] = cm;

        bf0 = nb0; bf1 = nb1; bptr = np;
    }

    // ---- row-min reduce: min over lanes 0..31 (cols) per half; rows = f(j,s,lh)
    float rowsum = 0.0f;
    #pragma unroll
    for (int s = 0; s < 2; ++s) {
        #pragma unroll
        for (int j = 0; j < 16; ++j) {
            float v = rmin[s][j];
            v = dpp_ror_min<0x121>(v);   // row_ror:1
            v = dpp_ror_min<0x122>(v);   // row_ror:2
            v = dpp_ror_min<0x124>(v);   // row_ror:4
            v = dpp_ror_min<0x128>(v);   // row_ror:8 -> per-16 min
            int sw = __builtin_amdgcn_ds_swizzle(__float_as_int(v), 0x401F); // xor16
            v = fminf(v, __int_as_float(sw));
            rowsum += v;                 // each (s,j,lh) is a distinct row
        }
    }
    if (l31 == 0) rowsumS[wave * 2 + lh] = rowsum;
    __syncthreads();

    // ---- cross-wave col-min merge + column sum (1 col per thread)
    {
        const int c = tid;
        float v = colW[c];
        #pragma unroll
        for (int w = 1; w < NWAVES; ++w) v = fminf(v, colW[w * 1024 + c]);
        float csum = v;
        #pragma unroll
        for (int off = 32; off > 0; off >>= 1) csum += __shfl_xor(csum, off, 64);
        if (lane == 0) redS[wave] = csum;
    }
    __syncthreads();

    if (tid == 0) {
        float rs = 0.0f, cs = 0.0f;
        #pragma unroll
        for (int w = 0; w < NWAVES; ++w) cs += redS[w];
        #pragma unroll
        for (int w = 0; w < 2 * NWAVES; ++w) rs += rowsumS[w];
        atomicAdd(out, rs * inv_bpm + cs * inv_bpn);
    }
}

extern "C" void kernel_launch(void* const* d_in, const int* in_sizes, int n_in,
                              void* d_out, int out_size, void* d_ws, size_t ws_size,
                              hipStream_t stream) {
    const float* nrf = (const float*)d_in[0];  // (B,P,N,3)
    const float* rp  = (const float*)d_in[1];  // (B,P,M,3)
    float* out = (float*)d_out;

    const int BP = in_sizes[1] / (MM * 3);     // 256
    const float inv_bpm = 1.0f / (float)(BP * MM);
    const float inv_bpn = 1.0f / (float)(BP * NN);

    (void)hipMemsetAsync(out, 0, sizeof(float), stream);
    chamfer_kernel<<<BP, THREADS, 0, stream>>>(nrf, rp, out, inv_bpm, inv_bpn);
}

// Round 3
// 99.110 us; speedup vs baseline: 1.0030x; 1.0030x over previous
//
#include <hip/hip_runtime.h>

// Chamfer loss: B=8, P=32, N=M=1024, fp32 in, scalar fp32 out.
// Reference quirk: x[bp,m,c] = rp[bp, (3m+c)%M, (3m+c)>>10]  (torch permute+reshape).
//
// R7: R6 with ONE change: pin occupancy with amdgpu_waves_per_eu(4,4).
// Diagnosis: R6's VGPR_Count=56 while ~100+ values are live => compiler banked
// rmin/acc into AGPRs (chasing occupancy that LDS already caps at 4 waves/EU),
// paying v_accvgpr_read/write around every fminf => ~5x dynamic VALU inflation
// (VALUBusy 62% with only ~13K cycles of source-level VALU per SIMD).
// waves_per_eu(4,4) removes the incentive: 128-reg budget, all state in arch
// VGPRs, no AGPR round-trips.
//
// Numerics (unchanged, bit-exact vs fp32 reference): dist = xx + yy - 2x.y via
// 3-way bf16 split (h0+h1+h2), 30 K-slots, 2x mfma_f32_32x32x16_bf16 per 32x32
// tile. 1024 threads / 16 waves; wave owns 64 rows = 2 stripes; 32 N-tiles.
// Row-min: rmin[2][16] regs + DPP ror(1,2,4,8) + swizzle xor16.
// Col-min: min3 tree + bpermute xor32 + colW[16][1024] overlay on dead A panel.

#define MM 1024
#define NN 1024
#define THREADS 1024
#define NWAVES 16
#define FINF 3.4e38f

typedef float f32x16 __attribute__((ext_vector_type(16)));
typedef __bf16 bf16x8 __attribute__((ext_vector_type(8)));

#define B_STRIDE 80                       // bytes per y-column (40 ushort slots)
#define A_STRIDE 64                       // bytes per x-row (32 ushort slots)
#define B_OFF 0
#define A_OFF (NN * B_STRIDE)             // 81920
#define CW_OFF A_OFF                      // overlay: colW[16][1024] f32 = 64KB
#define RS_OFF (A_OFF + MM * A_STRIDE)    // 147456
#define RED_OFF (RS_OFF + 128)            // 32 rowsum slots
#define LDS_BYTES (RED_OFF + 64)          // 147648

__device__ __forceinline__ unsigned short bf16_rne(float v) {
    unsigned u = __float_as_uint(v);
    u = u + 0x7FFFu + ((u >> 16) & 1u);
    return (unsigned short)(u >> 16);
}
__device__ __forceinline__ float bf16f(unsigned short h) {
    return __uint_as_float(((unsigned)h) << 16);
}
struct S3 { unsigned short h0, h1, h2; };
__device__ __forceinline__ S3 split3(float v) {
    S3 o;
    o.h0 = bf16_rne(v);
    float r = v - bf16f(o.h0);
    o.h1 = bf16_rne(r);
    float r2 = r - bf16f(o.h1);
    o.h2 = bf16_rne(r2);
    return o;
}
__device__ __forceinline__ unsigned pk(unsigned short a, unsigned short b) {
    return (unsigned)a | ((unsigned)b << 16);
}
__device__ __forceinline__ float min3f(float a, float b, float c) {
    return fminf(fminf(a, b), c);   // folds to v_min3_f32
}
template <int CTRL>
__device__ __forceinline__ float dpp_ror_min(float v) {
    int vi = __float_as_int(v);
    int t  = __builtin_amdgcn_update_dpp(vi, vi, CTRL, 0xf, 0xf, true);
    return fminf(v, __int_as_float(t));
}

__global__ __attribute__((amdgpu_flat_work_group_size(THREADS, THREADS),
                          amdgpu_waves_per_eu(4, 4)))
void chamfer_kernel(const float* __restrict__ nrf,   // (BP, N, 3) -> y
                    const float* __restrict__ rp,    // (BP, M, 3) -> x (scrambled)
                    float* __restrict__ out,
                    float inv_bpm, float inv_bpn) {
    __shared__ __align__(16) unsigned char smem[LDS_BYTES];
    unsigned char* Bb = smem + B_OFF;
    unsigned short* As = (unsigned short*)(smem + A_OFF);
    float* colW = (float*)(smem + CW_OFF);
    float* rowsumS = (float*)(smem + RS_OFF);
    float* redS = (float*)(smem + RED_OFF);

    const int bp = blockIdx.x;
    const int tid = threadIdx.x;
    const int lane = tid & 63;
    const int wave = tid >> 6;
    const int l31 = lane & 31;
    const int lh = lane >> 5;
    const unsigned short ONE = 0x3F80;

    const float* yB = nrf + (size_t)bp * NN * 3;
    const float* xB = rp + (size_t)bp * MM * 3;

    // ---- B panel: per col slots (b = y split, q = yy split)
    {
        const int c = tid;
        float y0 = yB[c * 3 + 0], y1 = yB[c * 3 + 1], y2 = yB[c * 3 + 2];
        float yy = __builtin_fmaf(y0, y0, __builtin_fmaf(y1, y1, y2 * y2));
        S3 b0 = split3(y0), b1 = split3(y1), b2 = split3(y2), q = split3(yy);
        uint4* dst = (uint4*)(Bb + c * B_STRIDE);
        dst[0] = make_uint4(pk(b0.h0, b0.h1), pk(b0.h0, b0.h1), pk(b0.h2, b0.h0), pk(b1.h0, b1.h1));
        dst[1] = make_uint4(pk(b1.h0, b1.h1), pk(b1.h2, b1.h0), pk(b2.h0, b2.h1), pk(b2.h0, b2.h1));
        dst[2] = make_uint4(pk(b2.h2, b2.h0), pk(ONE, ONE), pk(ONE, q.h0), pk(q.h1, q.h2));
        dst[3] = make_uint4(pk(b0.h2, b0.h1), pk(b1.h2, b1.h1), pk(b2.h2, b2.h1), 0u);
        dst[4] = make_uint4(0u, 0u, 0u, 0u);
    }
    // ---- A panel: per row slots (a = -2x split, p = xx split)
    {
        const int m = tid;
        int k = 3 * m;
        float x0 = xB[((k    ) & (MM - 1)) * 3 + ((k    ) >> 10)];
        float x1 = xB[((k + 1) & (MM - 1)) * 3 + ((k + 1) >> 10)];
        float x2 = xB[((k + 2) & (MM - 1)) * 3 + ((k + 2) >> 10)];
        float xx = __builtin_fmaf(x0, x0, __builtin_fmaf(x1, x1, x2 * x2));
        S3 a0 = split3(-2.0f * x0), a1 = split3(-2.0f * x1), a2 = split3(-2.0f * x2);
        S3 p = split3(xx);
        uint4* dst = (uint4*)((unsigned char*)As + m * A_STRIDE);
        dst[0] = make_uint4(pk(a0.h0, a0.h0), pk(a0.h1, a0.h1), pk(a0.h0, a0.h2), pk(a1.h0, a1.h0));
        dst[1] = make_uint4(pk(a1.h1, a1.h1), pk(a1.h0, a1.h2), pk(a2.h0, a2.h0), pk(a2.h1, a2.h1));
        dst[2] = make_uint4(pk(a2.h0, a2.h2), pk(p.h0, p.h1), pk(p.h2, ONE), pk(ONE, ONE));
        dst[3] = make_uint4(pk(a0.h1, a0.h2), pk(a1.h1, a1.h2), pk(a2.h1, a2.h2), 0u);
    }
    __syncthreads();

    // ---- A-fragment loads (once; rows fixed per wave): 2 stripes x 2 K-halves
    const int m0 = wave * 64;
    bf16x8 af[2][2];
    #pragma unroll
    for (int s = 0; s < 2; ++s) {
        #pragma unroll
        for (int h = 0; h < 2; ++h)
            af[s][h] = *(const bf16x8*)(As + (m0 + s * 32 + l31) * 32 + h * 16 + lh * 8);
    }
    __syncthreads();   // after this, A panel is colW

    float rmin[2][16];
    #pragma unroll
    for (int s = 0; s < 2; ++s)
        #pragma unroll
        for (int j = 0; j < 16; ++j) rmin[s][j] = FINF;

    f32x16 Z = {};
    const unsigned char* bptr = Bb + l31 * B_STRIDE + lh * 16;
    const int xaddr32 = (lane ^ 32) << 2;
    float* colWrow = colW + wave * 1024;

    bf16x8 bf0 = *(const bf16x8*)(bptr);
    bf16x8 bf1 = *(const bf16x8*)(bptr + 32);
    for (int t = 0; t < 32; ++t) {
        // prefetch next tile's B-frags (last iter reads dead LDS, values unused)
        const unsigned char* np = bptr + 32 * B_STRIDE;
        bf16x8 nb0 = *(const bf16x8*)(np);
        bf16x8 nb1 = *(const bf16x8*)(np + 32);

        float cm = FINF;
        #pragma unroll
        for (int s = 0; s < 2; ++s) {
            f32x16 acc = __builtin_amdgcn_mfma_f32_32x32x16_bf16(af[s][0], bf0, Z, 0, 0, 0);
            acc = __builtin_amdgcn_mfma_f32_32x32x16_bf16(af[s][1], bf1, acc, 0, 0, 0);
            #pragma unroll
            for (int j = 0; j < 16; ++j) rmin[s][j] = fminf(rmin[s][j], acc[j]);
            float u0 = min3f(acc[0], acc[1], acc[2]);
            float u1 = min3f(acc[3], acc[4], acc[5]);
            float u2 = min3f(acc[6], acc[7], acc[8]);
            float u3 = min3f(acc[9], acc[10], acc[11]);
            float u4 = min3f(acc[12], acc[13], acc[14]);
            cm = fminf(cm, fminf(min3f(u0, u1, u2), min3f(u3, u4, acc[15])));
        }
        // merge the two lane-halves -> full 64-row col-min for this wave
        int pz = __builtin_amdgcn_ds_bpermute(xaddr32, __float_as_int(cm));
        cm = fminf(cm, __int_as_float(pz));
        if (lh == 0) colWrow[t * 32 + l31] = cm;

        bf0 = nb0; bf1 = nb1; bptr = np;
    }

    // ---- row-min reduce: min over lanes 0..31 (cols) per half; rows = f(j,s,lh)
    float rowsum = 0.0f;
    #pragma unroll
    for (int s = 0; s < 2; ++s) {
        #pragma unroll
        for (int j = 0; j < 16; ++j) {
            float v = rmin[s][j];
            v = dpp_ror_min<0x121>(v);   // row_ror:1
            v = dpp_ror_min<0x122>(v);   // row_ror:2
            v = dpp_ror_min<0x124>(v);   // row_ror:4
            v = dpp_ror_min<0x128>(v);   // row_ror:8 -> per-16 min
            int sw = __builtin_amdgcn_ds_swizzle(__float_as_int(v), 0x401F); // xor16
            v = fminf(v, __int_as_float(sw));
            rowsum += v;                 // each (s,j,lh) is a distinct row
        }
    }
    if (l31 == 0) rowsumS[wave * 2 + lh] = rowsum;
    __syncthreads();

    // ---- cross-wave col-min merge + column sum (1 col per thread)
    {
        const int c = tid;
        float v = colW[c];
        #pragma unroll
        for (int w = 1; w < NWAVES; ++w) v = fminf(v, colW[w * 1024 + c]);
        float csum = v;
        #pragma unroll
        for (int off = 32; off > 0; off >>= 1) csum += __shfl_xor(csum, off, 64);
        if (lane == 0) redS[wave] = csum;
    }
    __syncthreads();

    if (tid == 0) {
        float rs = 0.0f, cs = 0.0f;
        #pragma unroll
        for (int w = 0; w < NWAVES; ++w) cs += redS[w];
        #pragma unroll
        for (int w = 0; w < 2 * NWAVES; ++w) rs += rowsumS[w];
        atomicAdd(out, rs * inv_bpm + cs * inv_bpn);
    }
}

extern "C" void kernel_launch(void* const* d_in, const int* in_sizes, int n_in,
                              void* d_out, int out_size, void* d_ws, size_t ws_size,
                              hipStream_t stream) {
    const float* nrf = (const float*)d_in[0];  // (B,P,N,3)
    const float* rp  = (const float*)d_in[1];  // (B,P,M,3)
    float* out = (float*)d_out;

    const int BP = in_sizes[1] / (MM * 3);     // 256
    const float inv_bpm = 1.0f / (float)(BP * MM);
    const float inv_bpn = 1.0f / (float)(BP * NN);

    (void)hipMemsetAsync(out, 0, sizeof(float), stream);
    chamfer_kernel<<<BP, THREADS, 0, stream>>>(nrf, rp, out, inv_bpm, inv_bpn);
}